// Round 16
// baseline (152.456 us; speedup 1.0000x reference)
//
#include <hip/hip_runtime.h>

#define CC 33
#define WAVE 64
#define BURN 8   // contraction ~0.23/step -> 0.23^8 ~ 8e-6 direction error

#if __has_builtin(__builtin_amdgcn_fdot2_f32_bf16)
#define HAS_BF16DOT 1
typedef __bf16 bfv2 __attribute__((ext_vector_type(2)));
#else
#define HAS_BF16DOT 0
#endif

__device__ __forceinline__ float wave_sum64(float v) {
#pragma unroll
  for (int k = 32; k >= 1; k >>= 1) v += __shfl_xor(v, k, 64);
  return v;
}

__device__ __forceinline__ float rl(float v, int lane) {
  return __uint_as_float(__builtin_amdgcn_readlane(__float_as_uint(v), lane));
}

// f32 fallback dot: s = sum_i rl(u,i) * etv[i]; 8 accumulators.
__device__ __forceinline__ float bdot33(float u, const float* etv) {
  float a0 = 0.f, a1 = 0.f, a2 = 0.f, a3 = 0.f;
  float a4 = 0.f, a5 = 0.f, a6 = 0.f, a7 = 0.f;
#pragma unroll
  for (int i = 0; i < 32; i += 8) {
    a0 = fmaf(rl(u, i + 0), etv[i + 0], a0);
    a1 = fmaf(rl(u, i + 1), etv[i + 1], a1);
    a2 = fmaf(rl(u, i + 2), etv[i + 2], a2);
    a3 = fmaf(rl(u, i + 3), etv[i + 3], a3);
    a4 = fmaf(rl(u, i + 4), etv[i + 4], a4);
    a5 = fmaf(rl(u, i + 5), etv[i + 5], a5);
    a6 = fmaf(rl(u, i + 6), etv[i + 6], a6);
    a7 = fmaf(rl(u, i + 7), etv[i + 7], a7);
  }
  a0 = fmaf(rl(u, 32), etv[32], a0);
  return (((a0 + a1) + (a2 + a3)) + ((a4 + a5) + (a6 + a7)));
}

#if HAS_BF16DOT
__device__ __forceinline__ bfv2 rlpk(unsigned v, int lane) {
  return __builtin_bit_cast(
      bfv2, (unsigned)__builtin_amdgcn_readlane((int)v, lane));
}
// bf16 dot2 dot: ppk lane i = (bf16(p_i), bf16(p_{i+1})); etp[q] = lane-local
// (etv[2q], etv[2q+1]) pairs. 17 readlane + 17 v_dot2_f32_bf16, f32 accum.
__device__ __forceinline__ float bdot33_bf16(unsigned ppk, const bfv2* etp) {
  float a0 = 0.f, a1 = 0.f, a2 = 0.f, a3 = 0.f;
#pragma unroll
  for (int q = 0; q < 16; q += 4) {
    a0 = __builtin_amdgcn_fdot2_f32_bf16(rlpk(ppk, 2 * q + 0), etp[q + 0], a0, false);
    a1 = __builtin_amdgcn_fdot2_f32_bf16(rlpk(ppk, 2 * q + 2), etp[q + 1], a1, false);
    a2 = __builtin_amdgcn_fdot2_f32_bf16(rlpk(ppk, 2 * q + 4), etp[q + 2], a2, false);
    a3 = __builtin_amdgcn_fdot2_f32_bf16(rlpk(ppk, 2 * q + 6), etp[q + 3], a3, false);
  }
  a0 = __builtin_amdgcn_fdot2_f32_bf16(rlpk(ppk, 32), etp[16], a0, false);
  return (a0 + a1) + (a2 + a3);
}
#endif

// ---------------------------------------------------------------------------
// Pack mask[b][t] (int) into bit-words + sequence lengths (popcount).
// ---------------------------------------------------------------------------
__global__ __launch_bounds__(WAVE) void pack_mask_kernel(
    const int* __restrict__ mask, unsigned long long* __restrict__ packed,
    int* __restrict__ lengths, int T) {
  const int b = blockIdx.x;
  const int l = threadIdx.x;
  const int* mb = mask + (size_t)b * T;
  const int W = T / 64;
  int cnt = 0;
  for (int w = 0; w < W; ++w) {
    unsigned long long bal = __ballot(mb[w * 64 + l] != 0);
    if (l == 0) {
      packed[(size_t)b * W + w] = bal;
      cnt += __popcll(bal);
    }
  }
  if (l == 0) lengths[b] = cnt;
}

// ---------------------------------------------------------------------------
// Chunked forward scan with IN-LOOP score fusion (R2 idiom):
//  - tags ring: 9-lane coalesced load (36 B) one macro ahead; per step the
//    (prev,cur) pair comes from two compile-time v_readlane.
//  - trans term: wave-uniform LDS broadcast read (no bank conflicts).
//  - emission term: v_readlane(emk, cur) -- em[t][:] is already in registers.
//  => all score operands wave-uniform: sc needs no reduction, no gathers
//     (R15's gather version cost +59 MB FETCH + 80k bank conflicts).
//  - renorm every 8 steps (growth e^{36+-6} << e^88 ceiling, 10-sigma margin).
// Burn-in macros excluded from score via uniform per-macro `owned` branch.
// ---------------------------------------------------------------------------
__global__ __launch_bounds__(WAVE)
__attribute__((amdgpu_waves_per_eu(8, 8)))
void crf_chunk_kernel(
    const float* __restrict__ emissions,
    const unsigned long long* __restrict__ pmask,
    const int* __restrict__ tags, const float* __restrict__ transitions,
    const float* __restrict__ start_t, const float* __restrict__ end_t,
    const float* __restrict__ tmask, const float* __restrict__ smask,
    const float* __restrict__ emask, float* __restrict__ contrib, int T, int B,
    int S, int K) {
  const int bid = blockIdx.x;
  const int c = bid / B;
  const int b = bid - c * B;
  const int j = threadIdx.x;
  const int jj = (j < CC) ? j : 0;
  const int W = T / 64;

  __shared__ float s_trans[CC * CC];
  for (int k = j; k < CC * CC; k += WAVE) s_trans[k] = transitions[k] + tmask[k];
  __syncthreads();

#if HAS_BF16DOT
  // lane j holds bf16 pairs (et[2q][j], et[2q+1][j]); zero for lanes >= CC.
  bfv2 etp[17];
#pragma unroll
  for (int q = 0; q < 17; ++q) {
    float v0 = (j < CC) ? __expf(s_trans[(2 * q) * CC + jj]) : 0.f;
    float v1 = (j < CC && 2 * q + 1 < CC)
                   ? __expf(s_trans[(2 * q + 1) * CC + jj]) : 0.f;
    bfv2 e;
    e[0] = (__bf16)v0;
    e[1] = (__bf16)v1;
    etp[q] = e;
  }
#else
  float etv[CC];
#pragma unroll
  for (int i = 0; i < CC; ++i)
    etv[i] = (j < CC) ? __expf(s_trans[i * CC + jj]) : 0.f;
#endif

  const float* __restrict__ emb = emissions + (size_t)b * T * CC;
  const unsigned long long* __restrict__ pkb = pmask + (size_t)b * W;
  const int* __restrict__ tagb = tags + (size_t)b * T;

  const int t_end = ((c + 1) * S < T - 1) ? (c + 1) * S : (T - 1);
  const int t_begin = (c == 0) ? 1 : c * S - (BURN - 1);
  const int NM = (c == 0) ? S / 8 : (S + BURN) / 8;
  const int OWN0 = (c == 0) ? 0 : (BURN / 8);  // first score-owned macro

  float p, logoff = 0.f, Lstart = 0.f;
  if (c == 0) {
    p = (j < CC) ? __expf(start_t[jj] + smask[jj] + emb[jj]) : 0.f;
  } else {
    p = (j < CC) ? 1.0f : 0.f;
  }

  // score accumulator (wave-uniform at all times)
  float sc = 0.f;
  if (c == 0) {
    int tag0 = tagb[0];
    sc = start_t[tag0] + smask[tag0] + emb[tag0];
  }

  int wcur = t_begin >> 6;
  unsigned long long mw0 = pkb[wcur];
  int wn1 = (wcur + 1 < W) ? wcur + 1 : W - 1;
  unsigned long long mw1 = pkb[wn1];

  float em_pre[8];
#pragma unroll
  for (int k = 0; k < 8; ++k) {
    int tp = t_begin + k;
    tp = tp > T - 1 ? T - 1 : tp;
    em_pre[k] = emb[(size_t)tp * CC + jj];
  }

  // tags ring: lane j<9 holds tags[t0-1+j]; prefetched one macro ahead.
  int tg = 0, tg_nxt;
  {
    int idx = t_begin - 1 + j;
    idx = idx > T - 1 ? T - 1 : idx;
    tg_nxt = (j < 9) ? tagb[idx] : 0;
  }

  int t0 = t_begin;
  for (int mm = 0; mm < NM; ++mm) {
    int w = t0 >> 6;
    if (w != wcur) {
      mw0 = mw1;
      wcur = w;
      int wn = (w + 1 < W) ? w + 1 : W - 1;
      mw1 = pkb[wn];
    }
    tg = tg_nxt;
    {
      int idx = t0 + 8 - 1 + j;
      idx = idx > T - 1 ? T - 1 : idx;
      tg_nxt = (j < 9) ? tagb[idx] : 0;
    }
    const bool owned = (mm >= OWN0);
    int mbit[8];
#pragma unroll
    for (int k = 0; k < 8; ++k) {
      int t = t0 + k;
      unsigned long long mw = ((t >> 6) == wcur) ? mw0 : mw1;
      mbit[k] = (int)((mw >> (t & 63)) & 1ull) & (t <= t_end ? 1 : 0);
    }
#pragma unroll
    for (int k = 0; k < 8; ++k) {
      float emk = em_pre[k];
      int mt = mbit[k];
      {
        int tp = t0 + 8 + k;
        tp = tp < 0 ? 0 : (tp > T - 1 ? T - 1 : tp);
        em_pre[k] = emb[(size_t)tp * CC + jj];
      }
      // ---- fused gold-path score (all operands wave-uniform) ----
      if (owned) {
        int prev = __builtin_amdgcn_readlane(tg, k);
        int cur = __builtin_amdgcn_readlane(tg, k + 1);
        float tsc = s_trans[prev * CC + cur];  // uniform LDS broadcast
        float esc = __uint_as_float(
            __builtin_amdgcn_readlane(__float_as_uint(emk), cur));
        sc += mt ? (tsc + esc) : 0.f;
      }
      float eemk = __expf(emk);
#if HAS_BF16DOT
      float pn1 = __shfl(p, j + 1, 64);  // lane 32 reads p_33 = 0 from lane 33
      unsigned ppk;
      asm("v_cvt_pk_bf16_f32 %0, %1, %2" : "=v"(ppk) : "v"(p), "v"(pn1));
      float s = bdot33_bf16(ppk, etp);
#else
      float s = bdot33(p, etv);
#endif
      if (k == 0) {  // renorm every 8 steps (growth e^36+-6 << e^88)
        float r = rl(p, 0);
        float rs = __builtin_amdgcn_rcpf(r);
        float pn = s * (eemk * rs);
        p = mt ? pn : p;
        logoff += mt ? __logf(r) : 0.f;
      } else {
        float pn = s * eemk;
        p = mt ? pn : p;
      }
    }
    t0 += 8;
    if (c > 0 && mm == (BURN / 8 - 1)) {
      Lstart = logoff + __logf(wave_sum64(p));
    }
  }

  float Lend;
  if (c == K - 1) {
    float eendv = (j < CC) ? __expf(end_t[jj] + emask[jj]) : 0.f;
    Lend = logoff + __logf(wave_sum64(p * eendv));
  } else {
    Lend = logoff + __logf(wave_sum64(p));
  }
  if (j == 0) contrib[(size_t)c * B + b] = (Lend - Lstart) - sc;
}

// out = mean_b( sum_c contrib[c][b] - end_term[b] );  end_term via lengths.
__global__ __launch_bounds__(512) void crf_finish_kernel(
    const float* __restrict__ contrib, const int* __restrict__ tags,
    const int* __restrict__ lengths, const float* __restrict__ end_t,
    const float* __restrict__ emask, float* __restrict__ out, int B, int K,
    int T) {
  const int b = threadIdx.x;  // one thread per sequence (B == 512)
  float v = 0.f;
  if (b < B) {
    for (int c = 0; c < K; ++c) v += contrib[(size_t)c * B + b];
    int len = lengths[b];
    if (len < 1) len = 1;
    int last = tags[(size_t)b * T + len - 1];
    v -= end_t[last] + emask[last];
  }
  v = wave_sum64(v);
  __shared__ float ws[8];
  if ((b & 63) == 0) ws[b >> 6] = v;
  __syncthreads();
  if (b == 0) {
    float s = 0.f;
    for (int q = 0; q < 8; ++q) s += ws[q];
    out[0] = s / (float)B;
  }
}

extern "C" void kernel_launch(void* const* d_in, const int* in_sizes, int n_in,
                              void* d_out, int out_size, void* d_ws, size_t ws_size,
                              hipStream_t stream) {
  const float* emissions = (const float*)d_in[0];
  const int* tags = (const int*)d_in[1];
  const int* mask = (const int*)d_in[2];
  const float* transitions = (const float*)d_in[3];
  const float* start_t = (const float*)d_in[4];
  const float* end_t = (const float*)d_in[5];
  const float* tmask = (const float*)d_in[6];
  const float* smask = (const float*)d_in[7];
  const float* emask = (const float*)d_in[8];

  const int T = 2048;          // fixed problem shape
  const int K = 16;            // chunks per sequence
  const int S = T / K;         // 128
  const int BT = in_sizes[1];  // B*T
  const int B = BT / T;
  const int W = T / 64;

  char* ws = (char*)d_ws;
  unsigned long long* packed = (unsigned long long*)ws;   // B*W u64
  float* contrib = (float*)(ws + (size_t)B * W * 8);      // K*B f
  int* lengths = (int*)(contrib + (size_t)K * B);         // B i32

  pack_mask_kernel<<<B, WAVE, 0, stream>>>(mask, packed, lengths, T);
  crf_chunk_kernel<<<K * B, WAVE, 0, stream>>>(
      emissions, packed, tags, transitions, start_t, end_t, tmask, smask,
      emask, contrib, T, B, S, K);
  crf_finish_kernel<<<1, 512, 0, stream>>>(contrib, tags, lengths, end_t,
                                           emask, (float*)d_out, B, K, T);
}

// Round 17
// 147.869 us; speedup vs baseline: 1.0310x; 1.0310x over previous
//
#include <hip/hip_runtime.h>

#define CC 33
#define WAVE 64
#define BURN 8   // contraction ~0.23/step -> 0.23^8 ~ 8e-6 direction error

#if __has_builtin(__builtin_amdgcn_fdot2_f32_bf16)
#define HAS_BF16DOT 1
typedef __bf16 bfv2 __attribute__((ext_vector_type(2)));
#else
#define HAS_BF16DOT 0
#endif

typedef unsigned long long ull;

__device__ __forceinline__ float wave_sum64(float v) {
#pragma unroll
  for (int k = 32; k >= 1; k >>= 1) v += __shfl_xor(v, k, 64);
  return v;
}

__device__ __forceinline__ float rl(float v, int lane) {
  return __uint_as_float(__builtin_amdgcn_readlane(__float_as_uint(v), lane));
}

// f32 fallback dot: s = sum_i rl(u,i) * etv[i]; 8 accumulators.
__device__ __forceinline__ float bdot33(float u, const float* etv) {
  float a0 = 0.f, a1 = 0.f, a2 = 0.f, a3 = 0.f;
  float a4 = 0.f, a5 = 0.f, a6 = 0.f, a7 = 0.f;
#pragma unroll
  for (int i = 0; i < 32; i += 8) {
    a0 = fmaf(rl(u, i + 0), etv[i + 0], a0);
    a1 = fmaf(rl(u, i + 1), etv[i + 1], a1);
    a2 = fmaf(rl(u, i + 2), etv[i + 2], a2);
    a3 = fmaf(rl(u, i + 3), etv[i + 3], a3);
    a4 = fmaf(rl(u, i + 4), etv[i + 4], a4);
    a5 = fmaf(rl(u, i + 5), etv[i + 5], a5);
    a6 = fmaf(rl(u, i + 6), etv[i + 6], a6);
    a7 = fmaf(rl(u, i + 7), etv[i + 7], a7);
  }
  a0 = fmaf(rl(u, 32), etv[32], a0);
  return (((a0 + a1) + (a2 + a3)) + ((a4 + a5) + (a6 + a7)));
}

#if HAS_BF16DOT
__device__ __forceinline__ bfv2 rlpk(unsigned v, int lane) {
  return __builtin_bit_cast(
      bfv2, (unsigned)__builtin_amdgcn_readlane((int)v, lane));
}
// bf16 dot2 dot: ppk lane i = (bf16(p_i), bf16(p_{i+1})); etp[q] = lane-local
// (etv[2q], etv[2q+1]) pairs. 17 readlane + 17 v_dot2_f32_bf16, f32 accum.
__device__ __forceinline__ float bdot33_bf16(unsigned ppk, const bfv2* etp) {
  float a0 = 0.f, a1 = 0.f, a2 = 0.f, a3 = 0.f;
#pragma unroll
  for (int q = 0; q < 16; q += 4) {
    a0 = __builtin_amdgcn_fdot2_f32_bf16(rlpk(ppk, 2 * q + 0), etp[q + 0], a0, false);
    a1 = __builtin_amdgcn_fdot2_f32_bf16(rlpk(ppk, 2 * q + 2), etp[q + 1], a1, false);
    a2 = __builtin_amdgcn_fdot2_f32_bf16(rlpk(ppk, 2 * q + 4), etp[q + 2], a2, false);
    a3 = __builtin_amdgcn_fdot2_f32_bf16(rlpk(ppk, 2 * q + 6), etp[q + 3], a3, false);
  }
  a0 = __builtin_amdgcn_fdot2_f32_bf16(rlpk(ppk, 32), etp[16], a0, false);
  return (a0 + a1) + (a2 + a3);
}
#endif

// ---------------------------------------------------------------------------
// Parallel mask pack: one wave per (b,w) word — single coalesced load +
// ballot + store. Replaces the 512-wave/32-serial-round version whose
// latency-bound cost (~15-20 us, 2 blocks/CU, nothing to hide under) was
// ~12% of total runtime (R14-R16 accounting).
// ---------------------------------------------------------------------------
__global__ __launch_bounds__(256) void pack_mask_kernel(
    const int* __restrict__ mask, ull* __restrict__ packed, int BW, int T) {
  const int task = blockIdx.x * 4 + (threadIdx.x >> 6);  // (b,w) index
  const int l = threadIdx.x & 63;
  if (task < BW) {
    const int b = task >> 5;  // W = 32 words per sequence (T = 2048)
    const int w = task & 31;
    ull bal = __ballot(mask[(size_t)b * T + w * 64 + l] != 0);
    if (l == 0) packed[task] = bal;
  }
}

// ---------------------------------------------------------------------------
// Chunked forward scan with in-loop score fusion (R16-proven, untouched):
//  - tags ring: 9-lane coalesced load one macro ahead; (prev,cur) via
//    compile-time v_readlane; trans term via uniform LDS broadcast;
//    emission term via v_readlane(emk, cur) — all operands wave-uniform.
//  - renorm every 8 steps (growth e^{36+-6} << e^88 ceiling).
// ---------------------------------------------------------------------------
__global__ __launch_bounds__(WAVE)
__attribute__((amdgpu_waves_per_eu(8, 8)))
void crf_chunk_kernel(
    const float* __restrict__ emissions, const ull* __restrict__ pmask,
    const int* __restrict__ tags, const float* __restrict__ transitions,
    const float* __restrict__ start_t, const float* __restrict__ end_t,
    const float* __restrict__ tmask, const float* __restrict__ smask,
    const float* __restrict__ emask, float* __restrict__ contrib, int T, int B,
    int S, int K) {
  const int bid = blockIdx.x;
  const int c = bid / B;
  const int b = bid - c * B;
  const int j = threadIdx.x;
  const int jj = (j < CC) ? j : 0;
  const int W = T / 64;

  __shared__ float s_trans[CC * CC];
  for (int k = j; k < CC * CC; k += WAVE) s_trans[k] = transitions[k] + tmask[k];
  __syncthreads();

#if HAS_BF16DOT
  // lane j holds bf16 pairs (et[2q][j], et[2q+1][j]); zero for lanes >= CC.
  bfv2 etp[17];
#pragma unroll
  for (int q = 0; q < 17; ++q) {
    float v0 = (j < CC) ? __expf(s_trans[(2 * q) * CC + jj]) : 0.f;
    float v1 = (j < CC && 2 * q + 1 < CC)
                   ? __expf(s_trans[(2 * q + 1) * CC + jj]) : 0.f;
    bfv2 e;
    e[0] = (__bf16)v0;
    e[1] = (__bf16)v1;
    etp[q] = e;
  }
#else
  float etv[CC];
#pragma unroll
  for (int i = 0; i < CC; ++i)
    etv[i] = (j < CC) ? __expf(s_trans[i * CC + jj]) : 0.f;
#endif

  const float* __restrict__ emb = emissions + (size_t)b * T * CC;
  const ull* __restrict__ pkb = pmask + (size_t)b * W;
  const int* __restrict__ tagb = tags + (size_t)b * T;

  const int t_end = ((c + 1) * S < T - 1) ? (c + 1) * S : (T - 1);
  const int t_begin = (c == 0) ? 1 : c * S - (BURN - 1);
  const int NM = (c == 0) ? S / 8 : (S + BURN) / 8;
  const int OWN0 = (c == 0) ? 0 : (BURN / 8);  // first score-owned macro

  float p, logoff = 0.f, Lstart = 0.f;
  if (c == 0) {
    p = (j < CC) ? __expf(start_t[jj] + smask[jj] + emb[jj]) : 0.f;
  } else {
    p = (j < CC) ? 1.0f : 0.f;
  }

  // score accumulator (wave-uniform at all times)
  float sc = 0.f;
  if (c == 0) {
    int tag0 = tagb[0];
    sc = start_t[tag0] + smask[tag0] + emb[tag0];
  }

  int wcur = t_begin >> 6;
  ull mw0 = pkb[wcur];
  int wn1 = (wcur + 1 < W) ? wcur + 1 : W - 1;
  ull mw1 = pkb[wn1];

  float em_pre[8];
#pragma unroll
  for (int k = 0; k < 8; ++k) {
    int tp = t_begin + k;
    tp = tp > T - 1 ? T - 1 : tp;
    em_pre[k] = emb[(size_t)tp * CC + jj];
  }

  // tags ring: lane j<9 holds tags[t0-1+j]; prefetched one macro ahead.
  int tg = 0, tg_nxt;
  {
    int idx = t_begin - 1 + j;
    idx = idx > T - 1 ? T - 1 : idx;
    tg_nxt = (j < 9) ? tagb[idx] : 0;
  }

  int t0 = t_begin;
  for (int mm = 0; mm < NM; ++mm) {
    int w = t0 >> 6;
    if (w != wcur) {
      mw0 = mw1;
      wcur = w;
      int wn = (w + 1 < W) ? w + 1 : W - 1;
      mw1 = pkb[wn];
    }
    tg = tg_nxt;
    {
      int idx = t0 + 8 - 1 + j;
      idx = idx > T - 1 ? T - 1 : idx;
      tg_nxt = (j < 9) ? tagb[idx] : 0;
    }
    const bool owned = (mm >= OWN0);
    int mbit[8];
#pragma unroll
    for (int k = 0; k < 8; ++k) {
      int t = t0 + k;
      ull mw = ((t >> 6) == wcur) ? mw0 : mw1;
      mbit[k] = (int)((mw >> (t & 63)) & 1ull) & (t <= t_end ? 1 : 0);
    }
#pragma unroll
    for (int k = 0; k < 8; ++k) {
      float emk = em_pre[k];
      int mt = mbit[k];
      {
        int tp = t0 + 8 + k;
        tp = tp < 0 ? 0 : (tp > T - 1 ? T - 1 : tp);
        em_pre[k] = emb[(size_t)tp * CC + jj];
      }
      // ---- fused gold-path score (all operands wave-uniform) ----
      if (owned) {
        int prev = __builtin_amdgcn_readlane(tg, k);
        int cur = __builtin_amdgcn_readlane(tg, k + 1);
        float tsc = s_trans[prev * CC + cur];  // uniform LDS broadcast
        float esc = __uint_as_float(
            __builtin_amdgcn_readlane(__float_as_uint(emk), cur));
        sc += mt ? (tsc + esc) : 0.f;
      }
      float eemk = __expf(emk);
#if HAS_BF16DOT
      float pn1 = __shfl(p, j + 1, 64);  // lane 32 reads p_33 = 0 from lane 33
      unsigned ppk;
      asm("v_cvt_pk_bf16_f32 %0, %1, %2" : "=v"(ppk) : "v"(p), "v"(pn1));
      float s = bdot33_bf16(ppk, etp);
#else
      float s = bdot33(p, etv);
#endif
      if (k == 0) {  // renorm every 8 steps (growth e^36+-6 << e^88)
        float r = rl(p, 0);
        float rs = __builtin_amdgcn_rcpf(r);
        float pn = s * (eemk * rs);
        p = mt ? pn : p;
        logoff += mt ? __logf(r) : 0.f;
      } else {
        float pn = s * eemk;
        p = mt ? pn : p;
      }
    }
    t0 += 8;
    if (c > 0 && mm == (BURN / 8 - 1)) {
      Lstart = logoff + __logf(wave_sum64(p));
    }
  }

  float Lend;
  if (c == K - 1) {
    float eendv = (j < CC) ? __expf(end_t[jj] + emask[jj]) : 0.f;
    Lend = logoff + __logf(wave_sum64(p * eendv));
  } else {
    Lend = logoff + __logf(wave_sum64(p));
  }
  if (j == 0) contrib[(size_t)c * B + b] = (Lend - Lstart) - sc;
}

// out = mean_b( sum_c contrib[c][b] - end_term[b] ).
// lengths derived here from packed words (popcount; 128 KB, L2/L3-resident) —
// keeps the pack kernel store-only and avoids atomics (graph-replay-unsafe
// without re-zeroing).
__global__ __launch_bounds__(512) void crf_finish_kernel(
    const float* __restrict__ contrib, const ull* __restrict__ packed,
    const int* __restrict__ tags, const float* __restrict__ end_t,
    const float* __restrict__ emask, float* __restrict__ out, int B, int K,
    int T) {
  const int b = threadIdx.x;  // one thread per sequence (B == 512)
  float v = 0.f;
  if (b < B) {
    for (int c = 0; c < K; ++c) v += contrib[(size_t)c * B + b];
    int len = 0;
#pragma unroll
    for (int w = 0; w < 32; ++w) len += __popcll(packed[(size_t)b * 32 + w]);
    if (len < 1) len = 1;
    int last = tags[(size_t)b * T + len - 1];
    v -= end_t[last] + emask[last];
  }
  v = wave_sum64(v);
  __shared__ float ws[8];
  if ((b & 63) == 0) ws[b >> 6] = v;
  __syncthreads();
  if (b == 0) {
    float s = 0.f;
    for (int q = 0; q < 8; ++q) s += ws[q];
    out[0] = s / (float)B;
  }
}

extern "C" void kernel_launch(void* const* d_in, const int* in_sizes, int n_in,
                              void* d_out, int out_size, void* d_ws, size_t ws_size,
                              hipStream_t stream) {
  const float* emissions = (const float*)d_in[0];
  const int* tags = (const int*)d_in[1];
  const int* mask = (const int*)d_in[2];
  const float* transitions = (const float*)d_in[3];
  const float* start_t = (const float*)d_in[4];
  const float* end_t = (const float*)d_in[5];
  const float* tmask = (const float*)d_in[6];
  const float* smask = (const float*)d_in[7];
  const float* emask = (const float*)d_in[8];

  const int T = 2048;          // fixed problem shape
  const int K = 16;            // chunks per sequence
  const int S = T / K;         // 128
  const int BT = in_sizes[1];  // B*T
  const int B = BT / T;
  const int W = T / 64;        // 32
  const int BW = B * W;

  char* ws = (char*)d_ws;
  ull* packed = (ull*)ws;                               // B*W u64
  float* contrib = (float*)(ws + (size_t)BW * 8);      // K*B f

  pack_mask_kernel<<<(BW + 3) / 4, 256, 0, stream>>>(mask, packed, BW, T);
  crf_chunk_kernel<<<K * B, WAVE, 0, stream>>>(
      emissions, packed, tags, transitions, start_t, end_t, tmask, smask,
      emask, contrib, T, B, S, K);
  crf_finish_kernel<<<1, 512, 0, stream>>>(contrib, packed, tags, end_t,
                                           emask, (float*)d_out, B, K, T);
}